// Round 1
// baseline (2864.151 us; speedup 1.0000x reference)
//
#include <hip/hip_runtime.h>
#include <math.h>

// ---------------- problem constants ----------------
#define NB 4
#define NS 2048
#define NTOK 8192          // B*S
#define ND 2048
#define NH 2048
#define NO 2048
#define NE 8
#define MATS 4194304       // 2048*2048 elements per weight matrix
#define NGRP 9             // 8 experts + shared (group 8)

// ---------------- ws layout (bytes) ----------------
// xbf:    ushort[8192*2048]                     =  33,554,432
// wbf:    ushort[27 * 4194304]  (w1 x8, w3 x8, w2 x8, sw1, sw3, sw2) = 226,492,416
// hid:    ushort[25600*2048]                    = 104,857,600
// tlist:  int[9*8192], wlist: float[9*8192], probs: float[8192*8], ctl ints
static constexpr size_t OFF_XBF   = 0;
static constexpr size_t OFF_WBF   = 33554432;
static constexpr size_t OFF_HID   = 260046848;
static constexpr size_t OFF_TLIST = 364904448;
static constexpr size_t OFF_WLIST = 365199360;
static constexpr size_t OFF_PROBS = 365494272;
static constexpr size_t OFF_CTL   = 365756416;

typedef __attribute__((ext_vector_type(8))) short bf16x8;
typedef __attribute__((ext_vector_type(4))) float f32x4;

__device__ __forceinline__ unsigned short f2bf(float f) {
    unsigned int u = __builtin_bit_cast(unsigned int, f);
    u = (u + 0x7fffu + ((u >> 16) & 1u)) >> 16;
    return (unsigned short)u;
}

__device__ __forceinline__ float gelu_exact(float x) {
    return 0.5f * x * (1.0f + erff(x * 0.70710678118654752f));
}

__device__ __forceinline__ void gload16(const unsigned short* g, unsigned short* l) {
    __builtin_amdgcn_global_load_lds(
        (const __attribute__((address_space(1))) void*)(g),
        (__attribute__((address_space(3))) void*)(l), 16, 0, 0);
}

// ---------------- fp32 -> bf16 conversion ----------------
__global__ __launch_bounds__(256) void cvt_kernel(const float* __restrict__ src,
                                                  unsigned short* __restrict__ dst, int n4) {
    for (int i = blockIdx.x * 256 + threadIdx.x; i < n4; i += gridDim.x * 256) {
        float4 v = ((const float4*)src)[i];
        ushort4 o;
        o.x = f2bf(v.x); o.y = f2bf(v.y); o.z = f2bf(v.z); o.w = f2bf(v.w);
        ((ushort4*)dst)[i] = o;
    }
}

// ---------------- router: logits, softmax, top-2, lists; also x->bf16 ----------------
__global__ __launch_bounds__(256) void router_kernel(
    const float* __restrict__ x, const float* __restrict__ rw, const float* __restrict__ rb,
    unsigned short* __restrict__ xbf, float* __restrict__ probs,
    int* __restrict__ tlist, float* __restrict__ wlist, int* __restrict__ cnt) {
    const int t = blockIdx.x;
    const int tid = threadIdx.x;
    const float* xr = x + (size_t)t * ND;
    float4 a0 = *(const float4*)(xr + tid * 8);
    float4 a1 = *(const float4*)(xr + tid * 8 + 4);

    // emit bf16 x row (coalesced 16B/thread)
    unsigned short* xo = xbf + (size_t)t * ND + tid * 8;
    ushort4 s0, s1;
    s0.x = f2bf(a0.x); s0.y = f2bf(a0.y); s0.z = f2bf(a0.z); s0.w = f2bf(a0.w);
    s1.x = f2bf(a1.x); s1.y = f2bf(a1.y); s1.z = f2bf(a1.z); s1.w = f2bf(a1.w);
    *(ushort4*)xo = s0;
    *(ushort4*)(xo + 4) = s1;

    float part[NE];
#pragma unroll
    for (int e = 0; e < NE; ++e) {
        const float* wr = rw + e * ND + tid * 8;
        float4 b0 = *(const float4*)(wr);
        float4 b1 = *(const float4*)(wr + 4);
        part[e] = a0.x * b0.x + a0.y * b0.y + a0.z * b0.z + a0.w * b0.w +
                  a1.x * b1.x + a1.y * b1.y + a1.z * b1.z + a1.w * b1.w;
    }
#pragma unroll
    for (int e = 0; e < NE; ++e)
        for (int off = 32; off > 0; off >>= 1) part[e] += __shfl_down(part[e], off);

    __shared__ float red[4][NE];
    const int lane = tid & 63, wid = tid >> 6;
    if (lane == 0) {
#pragma unroll
        for (int e = 0; e < NE; ++e) red[wid][e] = part[e];
    }
    __syncthreads();
    if (tid == 0) {
        float lg[NE];
#pragma unroll
        for (int e = 0; e < NE; ++e)
            lg[e] = red[0][e] + red[1][e] + red[2][e] + red[3][e] + rb[e];
        float m = lg[0];
#pragma unroll
        for (int e = 1; e < NE; ++e) m = fmaxf(m, lg[e]);
        float p[NE], s = 0.f;
#pragma unroll
        for (int e = 0; e < NE; ++e) { p[e] = expf(lg[e] - m); s += p[e]; }
        float inv = 1.0f / s;
#pragma unroll
        for (int e = 0; e < NE; ++e) { p[e] *= inv; probs[t * NE + e] = p[e]; }
        // top-2, stable (first index wins on ties) to match jax.lax.top_k
        int e0 = 0;
#pragma unroll
        for (int e = 1; e < NE; ++e) if (p[e] > p[e0]) e0 = e;
        int e1 = (e0 == 0) ? 1 : 0;
#pragma unroll
        for (int e = 0; e < NE; ++e) if (e != e0 && p[e] > p[e1]) e1 = e;
        float den = p[e0] + p[e1];
        float w0 = p[e0] / den, w1 = p[e1] / den;
        int pos0 = atomicAdd(&cnt[e0], 1);
        tlist[e0 * NTOK + pos0] = t; wlist[e0 * NTOK + pos0] = w0;
        int pos1 = atomicAdd(&cnt[e1], 1);
        tlist[e1 * NTOK + pos1] = t; wlist[e1 * NTOK + pos1] = w1;
    }
}

// ---------------- finalize: aux loss, pad lists, tile prefix ----------------
__global__ __launch_bounds__(256) void finalize_kernel(
    const float* __restrict__ probs, int* __restrict__ tlist, float* __restrict__ wlist,
    const int* __restrict__ cnt, int* __restrict__ tiles, int* __restrict__ hidrow,
    float* __restrict__ aux_out) {
    const int tid = threadIdx.x;
    float part[NE] = {0.f, 0.f, 0.f, 0.f, 0.f, 0.f, 0.f, 0.f};
    for (int t = tid; t < NTOK; t += 256) {
        const float* p = probs + t * NE;
#pragma unroll
        for (int e = 0; e < NE; ++e) part[e] += p[e];
    }
#pragma unroll
    for (int e = 0; e < NE; ++e)
        for (int off = 32; off > 0; off >>= 1) part[e] += __shfl_down(part[e], off);
    __shared__ float red[4][NE];
    const int lane = tid & 63, wid = tid >> 6;
    if (lane == 0) {
#pragma unroll
        for (int e = 0; e < NE; ++e) red[wid][e] = part[e];
    }
    __syncthreads();
    if (tid == 0) {
        float aux = 0.f;
#pragma unroll
        for (int e = 0; e < NE; ++e) {
            float u = (red[0][e] + red[1][e] + red[2][e] + red[3][e]) / (float)NTOK;
            aux += u * u;
        }
        *aux_out = aux * (float)NE * 0.001f;
    }
    // pad each expert list up to a multiple of 128 with (token 0, weight 0)
    for (int g = 0; g < NE; ++g) {
        int c = cnt[g];
        int pc = (c + 127) & ~127;
        for (int i = c + tid; i < pc; i += 256) {
            tlist[g * NTOK + i] = 0;
            wlist[g * NTOK + i] = 0.f;
        }
    }
    if (tid == 0) {
        int base = 0;
        for (int g = 0; g < NGRP; ++g) {
            int tg = (g == 8) ? (NTOK / 128) : ((cnt[g] + 127) >> 7);
            tiles[g] = tg;
            hidrow[g] = base;
            base += tg * 128;
        }
    }
}

// ---------------- pass 1: hid = gelu(x@w1^T+b1) * gelu(x@w3^T+b3), gathered ----------------
__global__ __launch_bounds__(256) void moe_gemm1(
    const unsigned short* __restrict__ xbf, const unsigned short* __restrict__ wbf,
    const float* __restrict__ b1e, const float* __restrict__ b3e,
    const float* __restrict__ sb1, const float* __restrict__ sb3,
    const int* __restrict__ tlist, const int* __restrict__ tiles,
    const int* __restrict__ hidrow, unsigned short* __restrict__ hid) {
    const int g = blockIdx.x >> 6;
    const int r = blockIdx.x & 63;
    if (r >= tiles[g]) return;
    const int cy = blockIdx.y;

    const unsigned short* W1 = wbf + (size_t)((g < 8) ? g : 24) * MATS;
    const unsigned short* W3 = wbf + (size_t)((g < 8) ? (8 + g) : 25) * MATS;
    const float* B1 = (g < 8) ? (b1e + g * NH) : sb1;
    const float* B3 = (g < 8) ? (b3e + g * NH) : sb3;

    __shared__ unsigned short lds[12288];  // A | W1 | W3, each 128x32 bf16
    const int tid = threadIdx.x;
    const int lane = tid & 63;
    const int wid = tid >> 6;
    const int wm = wid >> 1, wn = wid & 1;

    const int ch0 = tid, ch1 = tid + 256;
    const int row0 = ch0 >> 2, c0 = ch0 & 3;
    const int row1 = ch1 >> 2, c1 = ch1 & 3;
    int tok0, tok1;
    if (g < 8) {
        tok0 = tlist[g * NTOK + r * 128 + row0];
        tok1 = tlist[g * NTOK + r * 128 + row1];
    } else {
        tok0 = r * 128 + row0;
        tok1 = r * 128 + row1;
    }
    const int nb = cy * 128;
    const unsigned short* srcA0 = xbf + (size_t)tok0 * ND + c0 * 8;
    const unsigned short* srcA1 = xbf + (size_t)tok1 * ND + c1 * 8;
    const unsigned short* srcW10 = W1 + (size_t)(nb + row0) * ND + c0 * 8;
    const unsigned short* srcW11 = W1 + (size_t)(nb + row1) * ND + c1 * 8;
    const unsigned short* srcW30 = W3 + (size_t)(nb + row0) * ND + c0 * 8;
    const unsigned short* srcW31 = W3 + (size_t)(nb + row1) * ND + c1 * 8;

    unsigned short* ldsA = lds;
    unsigned short* ldsW1 = lds + 4096;
    unsigned short* ldsW3 = lds + 8192;
    unsigned short* dA0 = ldsA + wid * 512;
    unsigned short* dA1 = ldsA + 2048 + wid * 512;
    unsigned short* dW10 = ldsW1 + wid * 512;
    unsigned short* dW11 = ldsW1 + 2048 + wid * 512;
    unsigned short* dW30 = ldsW3 + wid * 512;
    unsigned short* dW31 = ldsW3 + 2048 + wid * 512;

    f32x4 acc1[4][4], acc3[4][4];
    const f32x4 z = {0.f, 0.f, 0.f, 0.f};
#pragma unroll
    for (int mi = 0; mi < 4; ++mi)
#pragma unroll
        for (int ni = 0; ni < 4; ++ni) { acc1[mi][ni] = z; acc3[mi][ni] = z; }

    const int arow = lane & 15;
    const int koff = (lane >> 4) * 8;

    for (int kk = 0; kk < ND; kk += 32) {
        __syncthreads();
        gload16(srcA0 + kk, dA0);
        gload16(srcA1 + kk, dA1);
        gload16(srcW10 + kk, dW10);
        gload16(srcW11 + kk, dW11);
        gload16(srcW30 + kk, dW30);
        gload16(srcW31 + kk, dW31);
        __syncthreads();

        bf16x8 af[4], f1[4], f3[4];
#pragma unroll
        for (int mi = 0; mi < 4; ++mi)
            af[mi] = *(const bf16x8*)(ldsA + (wm * 64 + mi * 16 + arow) * 32 + koff);
#pragma unroll
        for (int ni = 0; ni < 4; ++ni) {
            f1[ni] = *(const bf16x8*)(ldsW1 + (wn * 64 + ni * 16 + arow) * 32 + koff);
            f3[ni] = *(const bf16x8*)(ldsW3 + (wn * 64 + ni * 16 + arow) * 32 + koff);
        }
#pragma unroll
        for (int mi = 0; mi < 4; ++mi)
#pragma unroll
            for (int ni = 0; ni < 4; ++ni) {
                acc1[mi][ni] = __builtin_amdgcn_mfma_f32_16x16x32_bf16(af[mi], f1[ni], acc1[mi][ni], 0, 0, 0);
                acc3[mi][ni] = __builtin_amdgcn_mfma_f32_16x16x32_bf16(af[mi], f3[ni], acc3[mi][ni], 0, 0, 0);
            }
    }

    // epilogue: gelu(h1+b1)*gelu(h3+b3) -> bf16 hid
    const int hb = hidrow[g] + r * 128 + wm * 64;
    const int cb = cy * 128 + wn * 64 + (lane & 15);
    float bb1[4], bb3[4];
#pragma unroll
    for (int ni = 0; ni < 4; ++ni) { bb1[ni] = B1[cb + ni * 16]; bb3[ni] = B3[cb + ni * 16]; }
#pragma unroll
    for (int mi = 0; mi < 4; ++mi) {
#pragma unroll
        for (int q = 0; q < 4; ++q) {
            int rowg = hb + mi * 16 + ((lane >> 4) << 2) + q;
            unsigned short* hrow = hid + (size_t)rowg * NH + cb;
#pragma unroll
            for (int ni = 0; ni < 4; ++ni) {
                float h1 = gelu_exact(acc1[mi][ni][q] + bb1[ni]);
                float h3 = gelu_exact(acc3[mi][ni][q] + bb3[ni]);
                hrow[ni * 16] = f2bf(h1 * h3);
            }
        }
    }
}

// ---------------- pass 2: out += weight * (hid@w2^T + b2), scattered ----------------
__global__ __launch_bounds__(256) void moe_gemm2(
    const unsigned short* __restrict__ hid, const unsigned short* __restrict__ wbf,
    const float* __restrict__ b2e, const float* __restrict__ sb2,
    const int* __restrict__ tlist, const float* __restrict__ wlist,
    const int* __restrict__ tiles, const int* __restrict__ hidrow,
    float* __restrict__ out) {
    const int g = blockIdx.x >> 6;
    const int r = blockIdx.x & 63;
    if (r >= tiles[g]) return;
    const int cy = blockIdx.y;

    const unsigned short* W2 = wbf + (size_t)((g < 8) ? (16 + g) : 26) * MATS;
    const float* B2 = (g < 8) ? (b2e + g * NO) : sb2;

    __shared__ unsigned short lds[8192];  // A | W2
    const int tid = threadIdx.x;
    const int lane = tid & 63;
    const int wid = tid >> 6;
    const int wm = wid >> 1, wn = wid & 1;

    const int ch0 = tid, ch1 = tid + 256;
    const int row0 = ch0 >> 2, c0 = ch0 & 3;
    const int row1 = ch1 >> 2, c1 = ch1 & 3;
    const int hb = hidrow[g] + r * 128;
    const int nb = cy * 128;
    const unsigned short* srcA0 = hid + (size_t)(hb + row0) * NH + c0 * 8;
    const unsigned short* srcA1 = hid + (size_t)(hb + row1) * NH + c1 * 8;
    const unsigned short* srcW0 = W2 + (size_t)(nb + row0) * NH + c0 * 8;
    const unsigned short* srcW1 = W2 + (size_t)(nb + row1) * NH + c1 * 8;

    unsigned short* ldsA = lds;
    unsigned short* ldsW = lds + 4096;
    unsigned short* dA0 = ldsA + wid * 512;
    unsigned short* dA1 = ldsA + 2048 + wid * 512;
    unsigned short* dW0 = ldsW + wid * 512;
    unsigned short* dW1 = ldsW + 2048 + wid * 512;

    f32x4 acc[4][4];
    const f32x4 z = {0.f, 0.f, 0.f, 0.f};
#pragma unroll
    for (int mi = 0; mi < 4; ++mi)
#pragma unroll
        for (int ni = 0; ni < 4; ++ni) acc[mi][ni] = z;

    const int arow = lane & 15;
    const int koff = (lane >> 4) * 8;

    for (int kk = 0; kk < NH; kk += 32) {
        __syncthreads();
        gload16(srcA0 + kk, dA0);
        gload16(srcA1 + kk, dA1);
        gload16(srcW0 + kk, dW0);
        gload16(srcW1 + kk, dW1);
        __syncthreads();

        bf16x8 af[4], bf[4];
#pragma unroll
        for (int mi = 0; mi < 4; ++mi)
            af[mi] = *(const bf16x8*)(ldsA + (wm * 64 + mi * 16 + arow) * 32 + koff);
#pragma unroll
        for (int ni = 0; ni < 4; ++ni)
            bf[ni] = *(const bf16x8*)(ldsW + (wn * 64 + ni * 16 + arow) * 32 + koff);
#pragma unroll
        for (int mi = 0; mi < 4; ++mi)
#pragma unroll
            for (int ni = 0; ni < 4; ++ni)
                acc[mi][ni] = __builtin_amdgcn_mfma_f32_16x16x32_bf16(af[mi], bf[ni], acc[mi][ni], 0, 0, 0);
    }

    const int rb2 = r * 128 + wm * 64;
    const int cb2 = cy * 128 + wn * 64 + (lane & 15);
    float bb[4];
#pragma unroll
    for (int ni = 0; ni < 4; ++ni) bb[ni] = B2[cb2 + ni * 16];
#pragma unroll
    for (int mi = 0; mi < 4; ++mi) {
#pragma unroll
        for (int q = 0; q < 4; ++q) {
            int idx = rb2 + mi * 16 + ((lane >> 4) << 2) + q;
            int tok; float wgt;
            if (g < 8) { tok = tlist[g * NTOK + idx]; wgt = wlist[g * NTOK + idx]; }
            else       { tok = idx; wgt = 1.0f; }
            if (wgt != 0.0f) {
                float* orow = out + (size_t)tok * NO + cb2;
#pragma unroll
                for (int ni = 0; ni < 4; ++ni) {
                    float val = (acc[mi][ni][q] + bb[ni]) * wgt;
                    atomicAdd(orow + ni * 16, val);
                }
            }
        }
    }
}

// ---------------- launch ----------------
extern "C" void kernel_launch(void* const* d_in, const int* in_sizes, int n_in,
                              void* d_out, int out_size, void* d_ws, size_t ws_size,
                              hipStream_t stream) {
    const float* x   = (const float*)d_in[0];
    const float* rw  = (const float*)d_in[1];
    const float* rb  = (const float*)d_in[2];
    const float* w1  = (const float*)d_in[3];
    const float* b1  = (const float*)d_in[4];
    const float* w2  = (const float*)d_in[5];
    const float* b2  = (const float*)d_in[6];
    const float* w3  = (const float*)d_in[7];
    const float* b3  = (const float*)d_in[8];
    const float* sw1 = (const float*)d_in[9];
    const float* sb1 = (const float*)d_in[10];
    const float* sw2 = (const float*)d_in[11];
    const float* sb2 = (const float*)d_in[12];
    const float* sw3 = (const float*)d_in[13];
    const float* sb3 = (const float*)d_in[14];
    (void)in_sizes; (void)n_in; (void)out_size; (void)ws_size;

    char* ws = (char*)d_ws;
    unsigned short* xbf = (unsigned short*)(ws + OFF_XBF);
    unsigned short* wbf = (unsigned short*)(ws + OFF_WBF);
    unsigned short* hid = (unsigned short*)(ws + OFF_HID);
    int*   tlist = (int*)(ws + OFF_TLIST);
    float* wlist = (float*)(ws + OFF_WLIST);
    float* probs = (float*)(ws + OFF_PROBS);
    int*   ctl   = (int*)(ws + OFF_CTL);
    int* cnt = ctl;
    int* tiles = ctl + 16;
    int* hidrow = ctl + 32;
    float* out = (float*)d_out;

    hipMemsetAsync(d_out, 0, (size_t)NTOK * NO * 4, stream);
    hipMemsetAsync(cnt, 0, 64, stream);

    // weights -> bf16 (w1 stack, w3 stack, w2 stack, then shared)
    cvt_kernel<<<2048, 256, 0, stream>>>(w1,  wbf + (size_t)0 * MATS,  (NE * MATS) / 4);
    cvt_kernel<<<2048, 256, 0, stream>>>(w3,  wbf + (size_t)8 * MATS,  (NE * MATS) / 4);
    cvt_kernel<<<2048, 256, 0, stream>>>(w2,  wbf + (size_t)16 * MATS, (NE * MATS) / 4);
    cvt_kernel<<<512, 256, 0, stream>>>(sw1, wbf + (size_t)24 * MATS, MATS / 4);
    cvt_kernel<<<512, 256, 0, stream>>>(sw3, wbf + (size_t)25 * MATS, MATS / 4);
    cvt_kernel<<<512, 256, 0, stream>>>(sw2, wbf + (size_t)26 * MATS, MATS / 4);

    router_kernel<<<NTOK, 256, 0, stream>>>(x, rw, rb, xbf, probs, tlist, wlist, cnt);
    finalize_kernel<<<1, 256, 0, stream>>>(probs, tlist, wlist, cnt, tiles, hidrow,
                                           out + (size_t)NTOK * NO);

    dim3 grid(NGRP * 64, 16);
    moe_gemm1<<<grid, 256, 0, stream>>>(xbf, wbf, b1, b3, sb1, sb3, tlist, tiles, hidrow, hid);
    moe_gemm2<<<grid, 256, 0, stream>>>(hid, wbf, b2, sb2, tlist, wlist, tiles, hidrow, out);
}

// Round 2
// 2232.326 us; speedup vs baseline: 1.2830x; 1.2830x over previous
//
#include <hip/hip_runtime.h>
#include <math.h>

// ---------------- problem constants ----------------
#define NTOK 8192          // B*S
#define ND 2048
#define NH 2048
#define NO 2048
#define NE 8
#define MATS 4194304       // 2048*2048 elements per weight matrix
#define NGRP 9             // 8 experts + shared (group 8)
#define MAXWL 200          // max row-tiles: 136 expert + 64 shared (200 % 8 == 0)

// ---------------- ws layout (bytes) ----------------
static constexpr size_t OFF_XBF   = 0;
static constexpr size_t OFF_WBF   = 33554432;
static constexpr size_t OFF_HID   = 260046848;
static constexpr size_t OFF_TLIST = 364904448;
static constexpr size_t OFF_WLIST = 365199360;
static constexpr size_t OFF_PROBS = 365494272;
static constexpr size_t OFF_CTL   = 365756416;

typedef __attribute__((ext_vector_type(8))) short bf16x8;
typedef __attribute__((ext_vector_type(4))) float f32x4;

__device__ __forceinline__ unsigned short f2bf(float f) {
    unsigned int u = __builtin_bit_cast(unsigned int, f);
    u = (u + 0x7fffu + ((u >> 16) & 1u)) >> 16;
    return (unsigned short)u;
}

__device__ __forceinline__ float gelu_exact(float x) {
    return 0.5f * x * (1.0f + erff(x * 0.70710678118654752f));
}

__device__ __forceinline__ void gload16(const unsigned short* g, unsigned short* l) {
    __builtin_amdgcn_global_load_lds(
        (const __attribute__((address_space(1))) void*)(g),
        (__attribute__((address_space(3))) void*)(l), 16, 0, 0);
}

// ---------------- fp32 -> bf16 conversion ----------------
__global__ __launch_bounds__(256) void cvt_kernel(const float* __restrict__ src,
                                                  unsigned short* __restrict__ dst, int n4) {
    for (int i = blockIdx.x * 256 + threadIdx.x; i < n4; i += gridDim.x * 256) {
        float4 v = ((const float4*)src)[i];
        ushort4 o;
        o.x = f2bf(v.x); o.y = f2bf(v.y); o.z = f2bf(v.z); o.w = f2bf(v.w);
        ((ushort4*)dst)[i] = o;
    }
}

// ---------------- router: logits, softmax, top-2, lists; also x->bf16 ----------------
__global__ __launch_bounds__(256) void router_kernel(
    const float* __restrict__ x, const float* __restrict__ rw, const float* __restrict__ rb,
    unsigned short* __restrict__ xbf, float* __restrict__ probs,
    int* __restrict__ tlist, float* __restrict__ wlist, int* __restrict__ cnt) {
    const int t = blockIdx.x;
    const int tid = threadIdx.x;
    const float* xr = x + (size_t)t * ND;
    float4 a0 = *(const float4*)(xr + tid * 8);
    float4 a1 = *(const float4*)(xr + tid * 8 + 4);

    unsigned short* xo = xbf + (size_t)t * ND + tid * 8;
    ushort4 s0, s1;
    s0.x = f2bf(a0.x); s0.y = f2bf(a0.y); s0.z = f2bf(a0.z); s0.w = f2bf(a0.w);
    s1.x = f2bf(a1.x); s1.y = f2bf(a1.y); s1.z = f2bf(a1.z); s1.w = f2bf(a1.w);
    *(ushort4*)xo = s0;
    *(ushort4*)(xo + 4) = s1;

    float part[NE];
#pragma unroll
    for (int e = 0; e < NE; ++e) {
        const float* wr = rw + e * ND + tid * 8;
        float4 b0 = *(const float4*)(wr);
        float4 b1 = *(const float4*)(wr + 4);
        part[e] = a0.x * b0.x + a0.y * b0.y + a0.z * b0.z + a0.w * b0.w +
                  a1.x * b1.x + a1.y * b1.y + a1.z * b1.z + a1.w * b1.w;
    }
#pragma unroll
    for (int e = 0; e < NE; ++e)
        for (int off = 32; off > 0; off >>= 1) part[e] += __shfl_down(part[e], off);

    __shared__ float red[4][NE];
    const int lane = tid & 63, wid = tid >> 6;
    if (lane == 0) {
#pragma unroll
        for (int e = 0; e < NE; ++e) red[wid][e] = part[e];
    }
    __syncthreads();
    if (tid == 0) {
        float lg[NE];
#pragma unroll
        for (int e = 0; e < NE; ++e)
            lg[e] = red[0][e] + red[1][e] + red[2][e] + red[3][e] + rb[e];
        float m = lg[0];
#pragma unroll
        for (int e = 1; e < NE; ++e) m = fmaxf(m, lg[e]);
        float p[NE], s = 0.f;
#pragma unroll
        for (int e = 0; e < NE; ++e) { p[e] = expf(lg[e] - m); s += p[e]; }
        float inv = 1.0f / s;
#pragma unroll
        for (int e = 0; e < NE; ++e) { p[e] *= inv; probs[t * NE + e] = p[e]; }
        int e0 = 0;
#pragma unroll
        for (int e = 1; e < NE; ++e) if (p[e] > p[e0]) e0 = e;
        int e1 = (e0 == 0) ? 1 : 0;
#pragma unroll
        for (int e = 0; e < NE; ++e) if (e != e0 && p[e] > p[e1]) e1 = e;
        float den = p[e0] + p[e1];
        float w0 = p[e0] / den, w1 = p[e1] / den;
        int pos0 = atomicAdd(&cnt[e0], 1);
        tlist[e0 * NTOK + pos0] = t; wlist[e0 * NTOK + pos0] = w0;
        int pos1 = atomicAdd(&cnt[e1], 1);
        tlist[e1 * NTOK + pos1] = t; wlist[e1 * NTOK + pos1] = w1;
    }
}

// ---------------- finalize: aux loss, pad lists, work list + hid prefix ----------------
__global__ __launch_bounds__(256) void finalize_kernel(
    const float* __restrict__ probs, int* __restrict__ tlist, float* __restrict__ wlist,
    const int* __restrict__ cnt, int* __restrict__ wl, int* __restrict__ hidrow,
    float* __restrict__ aux_out) {
    const int tid = threadIdx.x;
    float part[NE] = {0.f, 0.f, 0.f, 0.f, 0.f, 0.f, 0.f, 0.f};
    for (int t = tid; t < NTOK; t += 256) {
        const float* p = probs + t * NE;
#pragma unroll
        for (int e = 0; e < NE; ++e) part[e] += p[e];
    }
#pragma unroll
    for (int e = 0; e < NE; ++e)
        for (int off = 32; off > 0; off >>= 1) part[e] += __shfl_down(part[e], off);
    __shared__ float red[4][NE];
    const int lane = tid & 63, wid = tid >> 6;
    if (lane == 0) {
#pragma unroll
        for (int e = 0; e < NE; ++e) red[wid][e] = part[e];
    }
    __syncthreads();
    if (tid == 0) {
        float aux = 0.f;
#pragma unroll
        for (int e = 0; e < NE; ++e) {
            float u = (red[0][e] + red[1][e] + red[2][e] + red[3][e]) / (float)NTOK;
            aux += u * u;
        }
        *aux_out = aux * (float)NE * 0.001f;
    }
    // pad each expert list up to a multiple of 128 with (token 0, weight 0)
    for (int g = 0; g < NE; ++g) {
        int c = cnt[g];
        int pc = (c + 127) & ~127;
        for (int i = c + tid; i < pc; i += 256) {
            tlist[g * NTOK + i] = 0;
            wlist[g * NTOK + i] = 0.f;
        }
    }
    if (tid == 0) {
        int idx = 0, base = 0;
        for (int g = 0; g < NGRP; ++g) {
            int tg = (g == 8) ? (NTOK / 128) : ((cnt[g] + 127) >> 7);
            hidrow[g] = base;
            base += tg * 128;
            for (int r = 0; r < tg; ++r) wl[idx++] = (g << 8) | r;
        }
        for (; idx < MAXWL; ++idx) wl[idx] = 0xFFFF;
    }
}

// LDS layout per stream (BK=32): [kc=4][row=128][8 bf16] = 4096 ushorts = 8KB.
// Slot s (16B) = kc*128 + row. Thread tid stages slots {tid, tid+256}:
//   row = tid&127, kc = tid>>7 and kc+2. LDS dest stays LINEAR (slot*16B) so
//   global_load_lds's wave-uniform-base+lane*16 contract holds; the kc-major
//   decode is applied to the per-lane GLOBAL source address (m173 pattern).
// Fragment read (row r, khalf h=lane>>4): ushort addr = (h*128 + r)*8 -> each
// quarter-wave reads 256 contiguous bytes = minimum bank cycles, no conflict.

// ---------------- pass 1: hid = gelu(x@w1^T+b1) * gelu(x@w3^T+b3), gathered ----------------
__global__ __launch_bounds__(256, 3) void moe_gemm1(
    const unsigned short* __restrict__ xbf, const unsigned short* __restrict__ wbf,
    const float* __restrict__ b1e, const float* __restrict__ b3e,
    const float* __restrict__ sb1, const float* __restrict__ sb3,
    const int* __restrict__ tlist, const int* __restrict__ wl,
    const int* __restrict__ hidrow, unsigned short* __restrict__ hid) {
    // XCD-aware swizzle over the dense work list (MAXWL % 8 == 0 -> bijective)
    const int d = blockIdx.x;
    const int e = wl[(d & 7) * (MAXWL / 8) + (d >> 3)];
    if (e == 0xFFFF) return;
    const int g = e >> 8, r = e & 255;
    const int cy = blockIdx.y;

    const unsigned short* W1 = wbf + (size_t)((g < 8) ? g : 24) * MATS;
    const unsigned short* W3 = wbf + (size_t)((g < 8) ? (8 + g) : 25) * MATS;
    const float* B1 = (g < 8) ? (b1e + g * NH) : sb1;
    const float* B3 = (g < 8) ? (b3e + g * NH) : sb3;

    __shared__ unsigned short lds[24576];  // 2 bufs x 3 streams x 4096 ushorts
    const int tid = threadIdx.x;
    const int lane = tid & 63;
    const int wid = tid >> 6;
    const int wm = wid >> 1, wn = wid & 1;

    // staging geometry
    const int srow = tid & 127;       // LDS row this thread stages
    const int skc = tid >> 7;         // kc for slot0; slot1 uses skc+2 (= +16 ushorts)
    int tok;
    if (g < 8) tok = tlist[g * NTOK + r * 128 + srow];
    else       tok = r * 128 + srow;
    const int nb = cy * 128;
    const unsigned short* sA = xbf + (size_t)tok * ND + skc * 8;
    const unsigned short* sW1 = W1 + (size_t)(nb + srow) * ND + skc * 8;
    const unsigned short* sW3 = W3 + (size_t)(nb + srow) * ND + skc * 8;
    unsigned short* dst = lds + tid * 8;  // slot0 dest; slot1 = +2048; stream stride 4096

    f32x4 acc1[4][4], acc3[4][4];
    const f32x4 z = {0.f, 0.f, 0.f, 0.f};
#pragma unroll
    for (int mi = 0; mi < 4; ++mi)
#pragma unroll
        for (int ni = 0; ni < 4; ++ni) { acc1[mi][ni] = z; acc3[mi][ni] = z; }

    const int arow = lane & 15;
    const int kh = lane >> 4;                 // k-half 0..3
    const int fA = (kh * 128 + wm * 64 + arow) * 8;
    const int fW = (kh * 128 + wn * 64 + arow) * 8;

    auto stage = [&](int buf, int kk) {
        unsigned short* b = dst + buf * 12288;
        gload16(sA + kk, b);
        gload16(sA + kk + 16, b + 2048);
        gload16(sW1 + kk, b + 4096);
        gload16(sW1 + kk + 16, b + 6144);
        gload16(sW3 + kk, b + 8192);
        gload16(sW3 + kk + 16, b + 10240);
    };

    stage(0, 0);
    int cur = 0;
    const int NIT = ND / 32;
    for (int it = 0; it < NIT; ++it) {
        __syncthreads();  // implicit vmcnt(0): buf[cur] staged; prev reads sealed
        if (it + 1 < NIT) stage(cur ^ 1, (it + 1) * 32);
        const unsigned short* bb = lds + cur * 12288;

        bf16x8 af[4], f1[4], f3[4];
#pragma unroll
        for (int mi = 0; mi < 4; ++mi)
            af[mi] = *(const bf16x8*)(bb + fA + mi * 128);
#pragma unroll
        for (int ni = 0; ni < 4; ++ni) {
            f1[ni] = *(const bf16x8*)(bb + 4096 + fW + ni * 128);
            f3[ni] = *(const bf16x8*)(bb + 8192 + fW + ni * 128);
        }
#pragma unroll
        for (int mi = 0; mi < 4; ++mi)
#pragma unroll
            for (int ni = 0; ni < 4; ++ni) {
                acc1[mi][ni] = __builtin_amdgcn_mfma_f32_16x16x32_bf16(af[mi], f1[ni], acc1[mi][ni], 0, 0, 0);
                acc3[mi][ni] = __builtin_amdgcn_mfma_f32_16x16x32_bf16(af[mi], f3[ni], acc3[mi][ni], 0, 0, 0);
            }
        cur ^= 1;
    }

    // epilogue: gelu(h1+b1)*gelu(h3+b3) -> bf16 hid
    const int hb = hidrow[g] + r * 128 + wm * 64;
    const int cb = cy * 128 + wn * 64 + arow;
    float bb1[4], bb3[4];
#pragma unroll
    for (int ni = 0; ni < 4; ++ni) { bb1[ni] = B1[cb + ni * 16]; bb3[ni] = B3[cb + ni * 16]; }
#pragma unroll
    for (int mi = 0; mi < 4; ++mi) {
#pragma unroll
        for (int q = 0; q < 4; ++q) {
            int rowg = hb + mi * 16 + (kh << 2) + q;
            unsigned short* hrow = hid + (size_t)rowg * NH + cb;
#pragma unroll
            for (int ni = 0; ni < 4; ++ni) {
                float h1 = gelu_exact(acc1[mi][ni][q] + bb1[ni]);
                float h3 = gelu_exact(acc3[mi][ni][q] + bb3[ni]);
                hrow[ni * 16] = f2bf(h1 * h3);
            }
        }
    }
}

// ---------------- pass 2: out += weight * (hid@w2^T + b2), scattered ----------------
__global__ __launch_bounds__(256, 3) void moe_gemm2(
    const unsigned short* __restrict__ hid, const unsigned short* __restrict__ wbf,
    const float* __restrict__ b2e, const float* __restrict__ sb2,
    const int* __restrict__ tlist, const float* __restrict__ wlist,
    const int* __restrict__ wl, const int* __restrict__ hidrow,
    float* __restrict__ out) {
    const int d = blockIdx.x;
    const int e = wl[(d & 7) * (MAXWL / 8) + (d >> 3)];
    if (e == 0xFFFF) return;
    const int g = e >> 8, r = e & 255;
    const int cy = blockIdx.y;

    const unsigned short* W2 = wbf + (size_t)((g < 8) ? (16 + g) : 26) * MATS;
    const float* B2 = (g < 8) ? (b2e + g * NO) : sb2;

    __shared__ unsigned short lds[16384];  // 2 bufs x 2 streams x 4096 ushorts
    const int tid = threadIdx.x;
    const int lane = tid & 63;
    const int wid = tid >> 6;
    const int wm = wid >> 1, wn = wid & 1;

    const int srow = tid & 127;
    const int skc = tid >> 7;
    const int hb = hidrow[g] + r * 128;
    const int nb = cy * 128;
    const unsigned short* sA = hid + (size_t)(hb + srow) * NH + skc * 8;
    const unsigned short* sW = W2 + (size_t)(nb + srow) * NH + skc * 8;
    unsigned short* dst = lds + tid * 8;

    f32x4 acc[4][4];
    const f32x4 z = {0.f, 0.f, 0.f, 0.f};
#pragma unroll
    for (int mi = 0; mi < 4; ++mi)
#pragma unroll
        for (int ni = 0; ni < 4; ++ni) acc[mi][ni] = z;

    const int arow = lane & 15;
    const int kh = lane >> 4;
    const int fA = (kh * 128 + wm * 64 + arow) * 8;
    const int fW = (kh * 128 + wn * 64 + arow) * 8;

    auto stage = [&](int buf, int kk) {
        unsigned short* b = dst + buf * 8192;
        gload16(sA + kk, b);
        gload16(sA + kk + 16, b + 2048);
        gload16(sW + kk, b + 4096);
        gload16(sW + kk + 16, b + 6144);
    };

    stage(0, 0);
    int cur = 0;
    const int NIT = NH / 32;
    for (int it = 0; it < NIT; ++it) {
        __syncthreads();
        if (it + 1 < NIT) stage(cur ^ 1, (it + 1) * 32);
        const unsigned short* bb = lds + cur * 8192;

        bf16x8 af[4], bf[4];
#pragma unroll
        for (int mi = 0; mi < 4; ++mi)
            af[mi] = *(const bf16x8*)(bb + fA + mi * 128);
#pragma unroll
        for (int ni = 0; ni < 4; ++ni)
            bf[ni] = *(const bf16x8*)(bb + 4096 + fW + ni * 128);
#pragma unroll
        for (int mi = 0; mi < 4; ++mi)
#pragma unroll
            for (int ni = 0; ni < 4; ++ni)
                acc[mi][ni] = __builtin_amdgcn_mfma_f32_16x16x32_bf16(af[mi], bf[ni], acc[mi][ni], 0, 0, 0);
        cur ^= 1;
    }

    const int rb2 = r * 128 + wm * 64;
    const int cb2 = cy * 128 + wn * 64 + arow;
    float bb[4];
#pragma unroll
    for (int ni = 0; ni < 4; ++ni) bb[ni] = B2[cb2 + ni * 16];
#pragma unroll
    for (int mi = 0; mi < 4; ++mi) {
#pragma unroll
        for (int q = 0; q < 4; ++q) {
            int idx = rb2 + mi * 16 + (kh << 2) + q;
            int tokd; float wgt;
            if (g < 8) { tokd = tlist[g * NTOK + idx]; wgt = wlist[g * NTOK + idx]; }
            else       { tokd = idx; wgt = 1.0f; }
            if (wgt != 0.0f) {
                float* orow = out + (size_t)tokd * NO + cb2;
#pragma unroll
                for (int ni = 0; ni < 4; ++ni) {
                    float val = (acc[mi][ni][q] + bb[ni]) * wgt;
                    atomicAdd(orow + ni * 16, val);
                }
            }
        }
    }
}

// ---------------- launch ----------------
extern "C" void kernel_launch(void* const* d_in, const int* in_sizes, int n_in,
                              void* d_out, int out_size, void* d_ws, size_t ws_size,
                              hipStream_t stream) {
    const float* x   = (const float*)d_in[0];
    const float* rw  = (const float*)d_in[1];
    const float* rb  = (const float*)d_in[2];
    const float* w1  = (const float*)d_in[3];
    const float* b1  = (const float*)d_in[4];
    const float* w2  = (const float*)d_in[5];
    const float* b2  = (const float*)d_in[6];
    const float* w3  = (const float*)d_in[7];
    const float* b3  = (const float*)d_in[8];
    const float* sw1 = (const float*)d_in[9];
    const float* sb1 = (const float*)d_in[10];
    const float* sw2 = (const float*)d_in[11];
    const float* sb2 = (const float*)d_in[12];
    const float* sw3 = (const float*)d_in[13];
    const float* sb3 = (const float*)d_in[14];
    (void)in_sizes; (void)n_in; (void)out_size; (void)ws_size;

    char* ws = (char*)d_ws;
    unsigned short* xbf = (unsigned short*)(ws + OFF_XBF);
    unsigned short* wbf = (unsigned short*)(ws + OFF_WBF);
    unsigned short* hid = (unsigned short*)(ws + OFF_HID);
    int*   tlist = (int*)(ws + OFF_TLIST);
    float* wlist = (float*)(ws + OFF_WLIST);
    float* probs = (float*)(ws + OFF_PROBS);
    int*   ctl   = (int*)(ws + OFF_CTL);
    int* cnt = ctl;
    int* hidrow = ctl + 32;
    int* wl = ctl + 48;
    float* out = (float*)d_out;

    hipMemsetAsync(d_out, 0, (size_t)NTOK * NO * 4, stream);
    hipMemsetAsync(cnt, 0, 64, stream);

    cvt_kernel<<<2048, 256, 0, stream>>>(w1,  wbf + (size_t)0 * MATS,  (NE * MATS) / 4);
    cvt_kernel<<<2048, 256, 0, stream>>>(w3,  wbf + (size_t)8 * MATS,  (NE * MATS) / 4);
    cvt_kernel<<<2048, 256, 0, stream>>>(w2,  wbf + (size_t)16 * MATS, (NE * MATS) / 4);
    cvt_kernel<<<512, 256, 0, stream>>>(sw1, wbf + (size_t)24 * MATS, MATS / 4);
    cvt_kernel<<<512, 256, 0, stream>>>(sw3, wbf + (size_t)25 * MATS, MATS / 4);
    cvt_kernel<<<512, 256, 0, stream>>>(sw2, wbf + (size_t)26 * MATS, MATS / 4);

    router_kernel<<<NTOK, 256, 0, stream>>>(x, rw, rb, xbf, probs, tlist, wlist, cnt);
    finalize_kernel<<<1, 256, 0, stream>>>(probs, tlist, wlist, cnt, wl, hidrow,
                                           out + (size_t)NTOK * NO);

    dim3 grid(MAXWL, 16);
    moe_gemm1<<<grid, 256, 0, stream>>>(xbf, wbf, b1, b3, sb1, sb3, tlist, wl, hidrow, hid);
    moe_gemm2<<<grid, 256, 0, stream>>>(hid, wbf, b2, sb2, tlist, wlist, wl, hidrow, out);
}